// Round 1
// 540.590 us; speedup vs baseline: 1.2737x; 1.2737x over previous
//
#include <hip/hip_runtime.h>
#include <math.h>

#define BN 8192
#define DD 4096
#define RK 16
#define HIDN 24
#define NCHUNK 32

// ws layout (float offsets). ps/pq alias T0T/T1T (re-zeroed after k1b).
#define OFF_T0T  0                           // 16*BN = 131072  (also ps)
#define OFF_T1T  (OFF_T0T + RK*BN)           // 131072          (also pq)
#define OFF_HT   (OFF_T1T + RK*BN)           // 262144 (32*BN = 262144, j-major)
#define OFF_XN2  (OFF_HT + 32*BN)            // 524288
#define OFF_X0N2 (OFF_XN2 + BN)              // 532480
#define ZCOUNT   (OFF_X0N2 + BN)             // 540672  (zeroed region)
#define OFF_V1T  (ZCOUNT)                    // 540672 (DD*RK = 65536)
#define OFF_MEAN (OFF_V1T + DD*RK)           // 606208
#define OFF_INV  (OFF_MEAN + DD)             // 610304
#define OFF_COEF (OFF_INV + DD)              // 614400
// total 622592 floats = 2.49 MB (< prior proven 2.95 MB footprint)

typedef __attribute__((ext_vector_type(8))) __bf16 bf16x8;
typedef __attribute__((ext_vector_type(4))) float f32x4;

// f32x8 -> bf16 hi + residual-lo frags (RNE via compiler casts)
__device__ inline void split8(const float* __restrict__ p, bf16x8& hi, bf16x8& lo) {
    float4 a = *(const float4*)p;
    float4 b = *(const float4*)(p + 4);
    float v[8] = {a.x, a.y, a.z, a.w, b.x, b.y, b.z, b.w};
#pragma unroll
    for (int j = 0; j < 8; ++j) {
        __bf16 h = (__bf16)v[j];
        hi[j] = h;
        lo[j] = (__bf16)(v[j] - (float)h);
    }
}

// ---------------- kT: v1 [16][4096] -> v1T [4096][16] -----------------------
__global__ __launch_bounds__(256) void kT(const float* __restrict__ v1,
                                          float* __restrict__ v1T) {
    int d = blockIdx.x * 256 + threadIdx.x;
    float v[16];
#pragma unroll
    for (int s = 0; s < 16; ++s) v[s] = v1[(size_t)s * DD + d];
#pragma unroll
    for (int s = 0; s < 4; ++s)
        *(float4*)(v1T + (size_t)d * 16 + s * 4) =
            make_float4(v[4 * s], v[4 * s + 1], v[4 * s + 2], v[4 * s + 3]);
}

// ---------------- K1a: per-column partial sums over 256-row chunks ----------
__global__ __launch_bounds__(256) void k1a(const float* __restrict__ g,
                                           float* __restrict__ ps,
                                           float* __restrict__ pq) {
    int ct = blockIdx.x & 15, rc = blockIdx.x >> 4;
    int col = ct * 256 + threadIdx.x;
    size_t base = (size_t)rc * 256 * DD + col;
    float s1 = 0.f, s2 = 0.f;
#pragma unroll 4
    for (int i = 0; i < 256; ++i) {
        float v = g[base + (size_t)i * DD];
        s1 += v;
        s2 = fmaf(v, v, s2);
    }
    ps[rc * DD + col] = s1;
    pq[rc * DD + col] = s2;
}

// ---------------- K1b: finalize mean / inv-std ------------------------------
__global__ __launch_bounds__(256) void k1b(const float* __restrict__ ps,
                                           const float* __restrict__ pq,
                                           float* __restrict__ meanw,
                                           float* __restrict__ invw) {
    int d = blockIdx.x * 256 + threadIdx.x;
    float s1 = 0.f, s2 = 0.f;
#pragma unroll
    for (int i = 0; i < NCHUNK; ++i) {
        s1 += ps[i * DD + d];
        s2 += pq[i * DD + d];
    }
    float mean = s1 / (float)BN;
    float var = (s2 - s1 * s1 / (float)BN) / (float)(BN - 1);
    var = fmaxf(var, 0.f);
    meanw[d] = mean;
    invw[d] = 1.f / (sqrtf(var) + 1e-7f);
}

// ---------------- K2m: MFMA  T0T[r][b] += v0 · x0  + X0N2 -------------------
// A-operand = v0 (N=16 rows), B-operand = x0^T. bf16 hi/lo 3-product split.
// grid 1024: (m-group of 32 rows) x (K quarter); wave = 256-wide K slice.
__global__ __launch_bounds__(256) void k2m(const float* __restrict__ grad,
                                           const float* __restrict__ meanw,
                                           const float* __restrict__ invw,
                                           const float* __restrict__ v0,
                                           float* __restrict__ T0T,
                                           float* __restrict__ X0N2) {
    __shared__ float red[4][512];
    int tid = threadIdx.x;
    int wv = tid >> 6, l = tid & 63;
    int lr = l & 15, lk = l >> 4;
    int m0 = (blockIdx.x >> 2) * 32;
    int kbase = (blockIdx.x & 3) * 1024 + wv * 256;
    const float* g0 = grad + (size_t)(m0 + lr) * DD + kbase + lk * 8;
    const float* vp = v0 + (size_t)lr * DD + kbase + lk * 8;
    const float* mp = meanw + kbase + lk * 8;
    const float* ip = invw + kbase + lk * 8;
    f32x4 acc[2] = {};
    float xs[2] = {0.f, 0.f};
#pragma unroll 2
    for (int ks = 0; ks < 8; ++ks) {
        int k0 = ks * 32;
        bf16x8 vhi, vlo;
        split8(vp + k0, vhi, vlo);
        float4 ma = *(const float4*)(mp + k0);
        float4 mb = *(const float4*)(mp + k0 + 4);
        float4 ia = *(const float4*)(ip + k0);
        float4 ib = *(const float4*)(ip + k0 + 4);
        float mv[8] = {ma.x, ma.y, ma.z, ma.w, mb.x, mb.y, mb.z, mb.w};
        float iv[8] = {ia.x, ia.y, ia.z, ia.w, ib.x, ib.y, ib.z, ib.w};
#pragma unroll
        for (int mt = 0; mt < 2; ++mt) {
            float4 ga = *(const float4*)(g0 + (size_t)(mt * 16) * DD + k0);
            float4 gb = *(const float4*)(g0 + (size_t)(mt * 16) * DD + k0 + 4);
            float gv[8] = {ga.x, ga.y, ga.z, ga.w, gb.x, gb.y, gb.z, gb.w};
            bf16x8 xhi, xlo;
            float ss = 0.f;
#pragma unroll
            for (int j = 0; j < 8; ++j) {
                float x = (gv[j] - mv[j]) * iv[j];
                ss = fmaf(x, x, ss);
                __bf16 h = (__bf16)x;
                xhi[j] = h;
                xlo[j] = (__bf16)(x - (float)h);
            }
            xs[mt] += ss;
            acc[mt] = __builtin_amdgcn_mfma_f32_16x16x32_bf16(vhi, xhi, acc[mt], 0, 0, 0);
            acc[mt] = __builtin_amdgcn_mfma_f32_16x16x32_bf16(vhi, xlo, acc[mt], 0, 0, 0);
            acc[mt] = __builtin_amdgcn_mfma_f32_16x16x32_bf16(vlo, xhi, acc[mt], 0, 0, 0);
        }
    }
    // X0N2: sum lane partials over the 4 k-subgroups, one atomic per row
    float s0 = xs[0], s1 = xs[1];
    s0 += __shfl_xor(s0, 16); s0 += __shfl_xor(s0, 32);
    s1 += __shfl_xor(s1, 16); s1 += __shfl_xor(s1, 32);
    if (l < 16) {
        atomicAdd(&X0N2[m0 + lr], s0);
        atomicAdd(&X0N2[m0 + 16 + lr], s1);
    }
    // cross-wave K reduction in LDS, then atomic partial into T0T
#pragma unroll
    for (int mt = 0; mt < 2; ++mt)
#pragma unroll
        for (int r = 0; r < 4; ++r)
            red[wv][mt * 256 + (lk * 4 + r) * 16 + lr] = acc[mt][r];
    __syncthreads();
    int o = tid * 2;
    int mt = (tid >> 7) & 1, nr = (tid >> 3) & 15;
#pragma unroll
    for (int j = 0; j < 2; ++j) {
        float s = red[0][o + j] + red[1][o + j] + red[2][o + j] + red[3][o + j];
        atomicAdd(&T0T[(size_t)nr * BN + m0 + mt * 16 + (o & 15) + j], s);
    }
}

// ---------------- K3: T1T[s][b] += v1T·relu(b0+u0·t0)  (no LDS) -------------
__global__ __launch_bounds__(256) void k3(const float* __restrict__ T0T,
                                          const float* __restrict__ u0,
                                          const float* __restrict__ b0,
                                          const float* __restrict__ v1T,
                                          float* __restrict__ T1T) {
    int b = (blockIdx.x >> 5) * 256 + threadIdx.x;
    int d0 = (blockIdx.x & 31) * 128;
    float t0[16];
#pragma unroll
    for (int r = 0; r < 16; ++r) t0[r] = T0T[(size_t)r * BN + b];
    float acc[16];
#pragma unroll
    for (int s = 0; s < 16; ++s) acc[s] = 0.f;
#pragma unroll 2
    for (int d = d0; d < d0 + 128; ++d) {
        const float* ur = u0 + (size_t)d * RK;       // uniform
        float x1 = b0[d];
#pragma unroll
        for (int r = 0; r < 16; ++r) x1 = fmaf(ur[r], t0[r], x1);
        x1 = fmaxf(x1, 0.f);
        const float* vr = v1T + (size_t)d * RK;      // uniform
#pragma unroll
        for (int s = 0; s < 16; ++s) acc[s] = fmaf(vr[s], x1, acc[s]);
    }
#pragma unroll
    for (int s = 0; s < 16; ++s)
        atomicAdd(&T1T[(size_t)s * BN + b], acc[s]);
}

// ---------------- K4: XN2[b] += sum_d relu(b1+u1·t1)^2  (no LDS) ------------
__global__ __launch_bounds__(256) void k4(const float* __restrict__ T1T,
                                          const float* __restrict__ u1,
                                          const float* __restrict__ b1,
                                          float* __restrict__ XN2) {
    int b = (blockIdx.x >> 5) * 256 + threadIdx.x;
    int d0 = (blockIdx.x & 31) * 128;
    float t1[16];
#pragma unroll
    for (int r = 0; r < 16; ++r) t1[r] = T1T[(size_t)r * BN + b];
    float acc = 0.f;
#pragma unroll 2
    for (int d = d0; d < d0 + 128; ++d) {
        const float* ur = u1 + (size_t)d * RK;       // uniform
        float x = b1[d];
#pragma unroll
        for (int r = 0; r < 16; ++r) x = fmaf(ur[r], t1[r], x);
        x = fmaxf(x, 0.f);
        acc = fmaf(x, x, acc);
    }
    atomicAdd(&XN2[b], acc);
}

// ---------------- K5m: MFMA  HT[j][b] += w1 · embed^T -----------------------
// A-operand = w1 (N=24 padded to 32), B-operand = embed^T. Same geometry as k2m.
__global__ __launch_bounds__(256) void k5m(const float* __restrict__ embed,
                                           const float* __restrict__ w1,
                                           float* __restrict__ HT) {
    __shared__ float red[4][1024];
    int tid = threadIdx.x;
    int wv = tid >> 6, l = tid & 63;
    int lr = l & 15, lk = l >> 4;
    int m0 = (blockIdx.x >> 2) * 32;
    int kbase = (blockIdx.x & 3) * 1024 + wv * 256;
    int wr1 = (lr + 16 > 23) ? 23 : lr + 16;         // clamp pad rows (junk -> unused HT rows)
    const float* e0 = embed + (size_t)(m0 + lr) * DD + kbase + lk * 8;
    const float* w0a = w1 + (size_t)lr * DD + kbase + lk * 8;
    const float* w0b = w1 + (size_t)wr1 * DD + kbase + lk * 8;
    f32x4 acc[2][2] = {};
#pragma unroll 2
    for (int ks = 0; ks < 8; ++ks) {
        int k0 = ks * 32;
        bf16x8 whi0, wlo0, whi1, wlo1;
        split8(w0a + k0, whi0, wlo0);
        split8(w0b + k0, whi1, wlo1);
#pragma unroll
        for (int mt = 0; mt < 2; ++mt) {
            bf16x8 ehi, elo;
            split8(e0 + (size_t)(mt * 16) * DD + k0, ehi, elo);
            acc[mt][0] = __builtin_amdgcn_mfma_f32_16x16x32_bf16(whi0, ehi, acc[mt][0], 0, 0, 0);
            acc[mt][1] = __builtin_amdgcn_mfma_f32_16x16x32_bf16(whi1, ehi, acc[mt][1], 0, 0, 0);
            acc[mt][0] = __builtin_amdgcn_mfma_f32_16x16x32_bf16(whi0, elo, acc[mt][0], 0, 0, 0);
            acc[mt][1] = __builtin_amdgcn_mfma_f32_16x16x32_bf16(whi1, elo, acc[mt][1], 0, 0, 0);
            acc[mt][0] = __builtin_amdgcn_mfma_f32_16x16x32_bf16(wlo0, ehi, acc[mt][0], 0, 0, 0);
            acc[mt][1] = __builtin_amdgcn_mfma_f32_16x16x32_bf16(wlo1, ehi, acc[mt][1], 0, 0, 0);
        }
    }
#pragma unroll
    for (int mt = 0; mt < 2; ++mt)
#pragma unroll
        for (int nt = 0; nt < 2; ++nt)
#pragma unroll
            for (int r = 0; r < 4; ++r)
                red[wv][(mt * 2 + nt) * 256 + (lk * 4 + r) * 16 + lr] = acc[mt][nt][r];
    __syncthreads();
    int o = tid * 4;
    int mt = (tid >> 7) & 1, nt = (tid >> 6) & 1, nr = (tid >> 2) & 15;
#pragma unroll
    for (int j = 0; j < 4; ++j) {
        float s = red[0][o + j] + red[1][o + j] + red[2][o + j] + red[3][o + j];
        atomicAdd(&HT[(size_t)(nt * 16 + nr) * BN + m0 + mt * 16 + (o & 15) + j], s);
    }
}

// ---------------- K5b: coeff = sigmoid(w2·relu(HT+bw1)+bw2) -----------------
__global__ __launch_bounds__(256) void k5b(const float* __restrict__ HT,
                                           const float* __restrict__ bw1,
                                           const float* __restrict__ w2,
                                           const float* __restrict__ bw2,
                                           float* __restrict__ COEF,
                                           float* __restrict__ out) {
    int b = blockIdx.x * 256 + threadIdx.x;
    float z = bw2[0];
#pragma unroll
    for (int j = 0; j < HIDN; ++j) {
        float h = fmaxf(HT[(size_t)j * BN + b] + bw1[j], 0.f);
        z = fmaf(w2[j], h, z);
    }
    float cf = 1.f / (1.f + expf(-z));
    COEF[b] = cf;
    out[(size_t)BN * DD + b] = cf;
}

__device__ inline float dotu(const float4* ur, const float* t, float b) {
    float a = b;
#pragma unroll
    for (int rr = 0; rr < 4; ++rr) {
        a = fmaf(ur[rr].x, t[4 * rr + 0], a);
        a = fmaf(ur[rr].y, t[4 * rr + 1], a);
        a = fmaf(ur[rr].z, t[4 * rr + 2], a);
        a = fmaf(ur[rr].w, t[4 * rr + 3], a);
    }
    return a;
}

// ---------------- K6: final blend + store -----------------------------------
__global__ __launch_bounds__(256) void k6(const float* __restrict__ grad,
                                          const float* __restrict__ meanw,
                                          const float* __restrict__ invw,
                                          const float* __restrict__ T1T,
                                          const float* __restrict__ u1,
                                          const float* __restrict__ b1,
                                          const float* __restrict__ XN2,
                                          const float* __restrict__ X0N2,
                                          const float* __restrict__ COEF,
                                          float* __restrict__ out) {
    int tid = threadIdx.x;
    int rt = blockIdx.x >> 2, ct = blockIdx.x & 3;
    int row0 = rt * 16, col0 = ct * 1024;
    int c = col0 + tid * 4;
    float4 u[4][4];
#pragma unroll
    for (int cc = 0; cc < 4; ++cc)
#pragma unroll
        for (int rr = 0; rr < 4; ++rr)
            u[cc][rr] = *(const float4*)(u1 + (size_t)(c + cc) * RK + rr * 4);
    float4 bv = *(const float4*)(b1 + c);
    float4 mv = *(const float4*)(meanw + c);
    float4 iv = *(const float4*)(invw + c);

    for (int row = 0; row < 16; ++row) {
        int b = row0 + row;
        float t[16];
#pragma unroll
        for (int r = 0; r < 16; ++r) t[r] = T1T[(size_t)r * BN + b];  // uniform
        float4 g = *(const float4*)(grad + (size_t)b * DD + c);
        float4 x0;
        x0.x = (g.x - mv.x) * iv.x;
        x0.y = (g.y - mv.y) * iv.y;
        x0.z = (g.z - mv.z) * iv.z;
        x0.w = (g.w - mv.w) * iv.w;
        float4 x2;
        x2.x = fmaxf(dotu(u[0], t, bv.x), 0.f);
        x2.y = fmaxf(dotu(u[1], t, bv.y), 0.f);
        x2.z = fmaxf(dotu(u[2], t, bv.z), 0.f);
        x2.w = fmaxf(dotu(u[3], t, bv.w), 0.f);
        float cf = COEF[b];                       // uniform
        float x0n = sqrtf(X0N2[b]) + 1e-8f;       // uniform
        float xn = sqrtf(XN2[b]) + 1e-8f;         // uniform
        float s1 = (1.f - cf) * x0n / xn;
        float4 o;
        o.x = fmaf(s1, x2.x, cf * x0.x);
        o.y = fmaf(s1, x2.y, cf * x0.y);
        o.z = fmaf(s1, x2.z, cf * x0.z);
        o.w = fmaf(s1, x2.w, cf * x0.w);
        *(float4*)(out + (size_t)b * DD + c) = o;
    }
}

extern "C" void kernel_launch(void* const* d_in, const int* in_sizes, int n_in,
                              void* d_out, int out_size, void* d_ws, size_t ws_size,
                              hipStream_t stream) {
    const float* grad = (const float*)d_in[0];
    const float* embed = (const float*)d_in[1];
    const float* u0 = (const float*)d_in[2];
    const float* v0 = (const float*)d_in[3];
    const float* b0 = (const float*)d_in[4];
    const float* u1 = (const float*)d_in[5];
    const float* v1 = (const float*)d_in[6];
    const float* b1 = (const float*)d_in[7];
    const float* w1 = (const float*)d_in[8];
    const float* bw1 = (const float*)d_in[9];
    const float* w2 = (const float*)d_in[10];
    const float* bw2 = (const float*)d_in[11];
    float* out = (float*)d_out;
    float* ws = (float*)d_ws;

    hipMemsetAsync(ws, 0, (size_t)ZCOUNT * sizeof(float), stream);

    kT<<<16, 256, 0, stream>>>(v1, ws + OFF_V1T);
    // embed pass first so grad (read by k1a just before k2m) stays L3-resident
    k5m<<<1024, 256, 0, stream>>>(embed, w1, ws + OFF_HT);
    k1a<<<512, 256, 0, stream>>>(grad, ws + OFF_T0T, ws + OFF_T1T);  // ps/pq alias
    k1b<<<16, 256, 0, stream>>>(ws + OFF_T0T, ws + OFF_T1T, ws + OFF_MEAN, ws + OFF_INV);
    // re-zero T0T/T1T (clobbered by ps/pq) before accumulation
    hipMemsetAsync(ws + OFF_T0T, 0, (size_t)(2 * RK * BN) * sizeof(float), stream);
    k2m<<<1024, 256, 0, stream>>>(grad, ws + OFF_MEAN, ws + OFF_INV, v0,
                                  ws + OFF_T0T, ws + OFF_X0N2);
    k3<<<1024, 256, 0, stream>>>(ws + OFF_T0T, u0, b0, ws + OFF_V1T, ws + OFF_T1T);
    k4<<<1024, 256, 0, stream>>>(ws + OFF_T1T, u1, b1, ws + OFF_XN2);
    k5b<<<32, 256, 0, stream>>>(ws + OFF_HT, bw1, w2, bw2, ws + OFF_COEF, out);
    k6<<<2048, 256, 0, stream>>>(grad, ws + OFF_MEAN, ws + OFF_INV, ws + OFF_T1T,
                                 u1, b1, ws + OFF_XN2, ws + OFF_X0N2,
                                 ws + OFF_COEF, out);
}

// Round 2
// 494.536 us; speedup vs baseline: 1.3923x; 1.0931x over previous
//
#include <hip/hip_runtime.h>
#include <math.h>

#define BN 8192
#define DD 4096
#define RK 16
#define HIDN 24
#define NCHUNK 128

// ws layout (float offsets). ps/pq now have their own region (no aliasing,
// no second memset). Total 1654784 floats = 6.6 MB.
#define OFF_T0T  0                           // 16*BN = 131072
#define OFF_T1T  (OFF_T0T + RK*BN)           // 131072
#define OFF_HT   (OFF_T1T + RK*BN)           // 262144 (32*BN, j-major)
#define ZCOUNT   (OFF_HT + 32*BN)            // 524288 zeroed (atomic targets)
#define OFF_PS   (ZCOUNT)                    // 128*DD = 524288
#define OFF_PQ   (OFF_PS + NCHUNK*DD)        // 524288
#define OFF_V1T  (OFF_PQ + NCHUNK*DD)        // 65536
#define OFF_MEAN (OFF_V1T + DD*RK)
#define OFF_INV  (OFF_MEAN + DD)
#define OFF_COEF (OFF_INV + DD)

typedef __attribute__((ext_vector_type(8))) __bf16 bf16x8;
typedef __attribute__((ext_vector_type(4))) float f32x4;

// f32x8 -> bf16 hi + residual-lo frags (RNE via compiler casts)
__device__ inline void split8(const float* __restrict__ p, bf16x8& hi, bf16x8& lo) {
    float4 a = *(const float4*)p;
    float4 b = *(const float4*)(p + 4);
    float v[8] = {a.x, a.y, a.z, a.w, b.x, b.y, b.z, b.w};
#pragma unroll
    for (int j = 0; j < 8; ++j) {
        __bf16 h = (__bf16)v[j];
        hi[j] = h;
        lo[j] = (__bf16)(v[j] - (float)h);
    }
}

// ---------------- kT: v1 [16][4096] -> v1T [4096][16] -----------------------
__global__ __launch_bounds__(256) void kT(const float* __restrict__ v1,
                                          float* __restrict__ v1T) {
    int d = blockIdx.x * 256 + threadIdx.x;
    float v[16];
#pragma unroll
    for (int s = 0; s < 16; ++s) v[s] = v1[(size_t)s * DD + d];
#pragma unroll
    for (int s = 0; s < 4; ++s)
        *(float4*)(v1T + (size_t)d * 16 + s * 4) =
            make_float4(v[4 * s], v[4 * s + 1], v[4 * s + 2], v[4 * s + 3]);
}

// ---------------- K1a: per-column partial sums, float4, 64-row chunks -------
__global__ __launch_bounds__(256) void k1a(const float* __restrict__ g,
                                           float* __restrict__ ps,
                                           float* __restrict__ pq) {
    int ct = blockIdx.x & 3, rc = blockIdx.x >> 2;   // 4 col-tiles x 128 chunks
    int col = ct * 1024 + threadIdx.x * 4;
    size_t base = (size_t)rc * 64 * DD + col;
    float4 s1 = make_float4(0.f, 0.f, 0.f, 0.f);
    float4 s2 = make_float4(0.f, 0.f, 0.f, 0.f);
#pragma unroll 8
    for (int i = 0; i < 64; ++i) {
        float4 v = *(const float4*)(g + base + (size_t)i * DD);
        s1.x += v.x; s1.y += v.y; s1.z += v.z; s1.w += v.w;
        s2.x = fmaf(v.x, v.x, s2.x);
        s2.y = fmaf(v.y, v.y, s2.y);
        s2.z = fmaf(v.z, v.z, s2.z);
        s2.w = fmaf(v.w, v.w, s2.w);
    }
    *(float4*)(ps + (size_t)rc * DD + col) = s1;
    *(float4*)(pq + (size_t)rc * DD + col) = s2;
}

// ---------------- K1b: finalize mean / inv-std ------------------------------
__global__ __launch_bounds__(256) void k1b(const float* __restrict__ ps,
                                           const float* __restrict__ pq,
                                           float* __restrict__ meanw,
                                           float* __restrict__ invw) {
    int d = blockIdx.x * 256 + threadIdx.x;
    float s1 = 0.f, s2 = 0.f;
#pragma unroll 8
    for (int i = 0; i < NCHUNK; ++i) {
        s1 += ps[i * DD + d];
        s2 += pq[i * DD + d];
    }
    float mean = s1 / (float)BN;
    float var = (s2 - s1 * s1 / (float)BN) / (float)(BN - 1);
    var = fmaxf(var, 0.f);
    meanw[d] = mean;
    invw[d] = 1.f / (sqrtf(var) + 1e-7f);
}

// ---------------- K2m: MFMA  T0T[r][b] += v0 · x0 ---------------------------
// 16-row m-groups (grid 2048 = 512 m x 4 K-quarters) for 8 blocks/CU.
__global__ __launch_bounds__(256) void k2m(const float* __restrict__ grad,
                                           const float* __restrict__ meanw,
                                           const float* __restrict__ invw,
                                           const float* __restrict__ v0,
                                           float* __restrict__ T0T) {
    __shared__ float red[4][256];
    int tid = threadIdx.x;
    int wv = tid >> 6, l = tid & 63;
    int lr = l & 15, lk = l >> 4;
    int m0 = (blockIdx.x >> 2) * 16;
    int kbase = (blockIdx.x & 3) * 1024 + wv * 256;
    const float* g0 = grad + (size_t)(m0 + lr) * DD + kbase + lk * 8;
    const float* vp = v0 + (size_t)lr * DD + kbase + lk * 8;
    const float* mp = meanw + kbase + lk * 8;
    const float* ip = invw + kbase + lk * 8;
    f32x4 acc = {0.f, 0.f, 0.f, 0.f};
#pragma unroll 2
    for (int ks = 0; ks < 8; ++ks) {
        int k0 = ks * 32;
        bf16x8 vhi, vlo;
        split8(vp + k0, vhi, vlo);
        float4 ma = *(const float4*)(mp + k0);
        float4 mb = *(const float4*)(mp + k0 + 4);
        float4 ia = *(const float4*)(ip + k0);
        float4 ib = *(const float4*)(ip + k0 + 4);
        float mv[8] = {ma.x, ma.y, ma.z, ma.w, mb.x, mb.y, mb.z, mb.w};
        float iv[8] = {ia.x, ia.y, ia.z, ia.w, ib.x, ib.y, ib.z, ib.w};
        float4 ga = *(const float4*)(g0 + k0);
        float4 gb = *(const float4*)(g0 + k0 + 4);
        float gv[8] = {ga.x, ga.y, ga.z, ga.w, gb.x, gb.y, gb.z, gb.w};
        bf16x8 xhi, xlo;
#pragma unroll
        for (int j = 0; j < 8; ++j) {
            float x = (gv[j] - mv[j]) * iv[j];
            __bf16 h = (__bf16)x;
            xhi[j] = h;
            xlo[j] = (__bf16)(x - (float)h);
        }
        acc = __builtin_amdgcn_mfma_f32_16x16x32_bf16(vhi, xhi, acc, 0, 0, 0);
        acc = __builtin_amdgcn_mfma_f32_16x16x32_bf16(vhi, xlo, acc, 0, 0, 0);
        acc = __builtin_amdgcn_mfma_f32_16x16x32_bf16(vlo, xhi, acc, 0, 0, 0);
    }
#pragma unroll
    for (int r = 0; r < 4; ++r)
        red[wv][(lk * 4 + r) * 16 + lr] = acc[r];
    __syncthreads();
    float s = red[0][tid] + red[1][tid] + red[2][tid] + red[3][tid];
    atomicAdd(&T0T[(size_t)(tid >> 4) * BN + m0 + (tid & 15)], s);
}

// ---------------- K3: T1T[s][b] += v1T·relu(b0+u0·t0)  (no LDS) -------------
__global__ __launch_bounds__(256) void k3(const float* __restrict__ T0T,
                                          const float* __restrict__ u0,
                                          const float* __restrict__ b0,
                                          const float* __restrict__ v1T,
                                          float* __restrict__ T1T) {
    int b = (blockIdx.x >> 5) * 256 + threadIdx.x;
    int d0 = (blockIdx.x & 31) * 128;
    float t0[16];
#pragma unroll
    for (int r = 0; r < 16; ++r) t0[r] = T0T[(size_t)r * BN + b];
    float acc[16];
#pragma unroll
    for (int s = 0; s < 16; ++s) acc[s] = 0.f;
#pragma unroll 2
    for (int d = d0; d < d0 + 128; ++d) {
        const float* ur = u0 + (size_t)d * RK;       // uniform
        float x1 = b0[d];
#pragma unroll
        for (int r = 0; r < 16; ++r) x1 = fmaf(ur[r], t0[r], x1);
        x1 = fmaxf(x1, 0.f);
        const float* vr = v1T + (size_t)d * RK;      // uniform
#pragma unroll
        for (int s = 0; s < 16; ++s) acc[s] = fmaf(vr[s], x1, acc[s]);
    }
#pragma unroll
    for (int s = 0; s < 16; ++s)
        atomicAdd(&T1T[(size_t)s * BN + b], acc[s]);
}

// ---------------- K5m: MFMA  HT[j][b] += w1 · embed^T -----------------------
// 16-row m-groups (grid 2048) for 8 blocks/CU. N=24 padded to 32 (clamped).
__global__ __launch_bounds__(256) void k5m(const float* __restrict__ embed,
                                           const float* __restrict__ w1,
                                           float* __restrict__ HT) {
    __shared__ float red[4][512];
    int tid = threadIdx.x;
    int wv = tid >> 6, l = tid & 63;
    int lr = l & 15, lk = l >> 4;
    int m0 = (blockIdx.x >> 2) * 16;
    int kbase = (blockIdx.x & 3) * 1024 + wv * 256;
    int wr1 = (lr + 16 > 23) ? 23 : lr + 16;         // clamp pad rows
    const float* e0 = embed + (size_t)(m0 + lr) * DD + kbase + lk * 8;
    const float* w0a = w1 + (size_t)lr * DD + kbase + lk * 8;
    const float* w0b = w1 + (size_t)wr1 * DD + kbase + lk * 8;
    f32x4 acc0 = {0.f, 0.f, 0.f, 0.f};
    f32x4 acc1 = {0.f, 0.f, 0.f, 0.f};
#pragma unroll 2
    for (int ks = 0; ks < 8; ++ks) {
        int k0 = ks * 32;
        bf16x8 whi0, wlo0, whi1, wlo1, ehi, elo;
        split8(w0a + k0, whi0, wlo0);
        split8(w0b + k0, whi1, wlo1);
        split8(e0 + k0, ehi, elo);
        acc0 = __builtin_amdgcn_mfma_f32_16x16x32_bf16(whi0, ehi, acc0, 0, 0, 0);
        acc1 = __builtin_amdgcn_mfma_f32_16x16x32_bf16(whi1, ehi, acc1, 0, 0, 0);
        acc0 = __builtin_amdgcn_mfma_f32_16x16x32_bf16(whi0, elo, acc0, 0, 0, 0);
        acc1 = __builtin_amdgcn_mfma_f32_16x16x32_bf16(whi1, elo, acc1, 0, 0, 0);
        acc0 = __builtin_amdgcn_mfma_f32_16x16x32_bf16(wlo0, ehi, acc0, 0, 0, 0);
        acc1 = __builtin_amdgcn_mfma_f32_16x16x32_bf16(wlo1, ehi, acc1, 0, 0, 0);
    }
#pragma unroll
    for (int r = 0; r < 4; ++r) {
        red[wv][(lk * 4 + r) * 16 + lr] = acc0[r];
        red[wv][256 + (lk * 4 + r) * 16 + lr] = acc1[r];
    }
    __syncthreads();
#pragma unroll
    for (int j = 0; j < 2; ++j) {
        int idx = tid + j * 256;
        float s = red[0][idx] + red[1][idx] + red[2][idx] + red[3][idx];
        int nt = idx >> 8, nr = (idx >> 4) & 15, cc = idx & 15;
        atomicAdd(&HT[(size_t)(nt * 16 + nr) * BN + m0 + cc], s);
    }
}

// ---------------- K5b: coeff = sigmoid(w2·relu(HT+bw1)+bw2) -----------------
__global__ __launch_bounds__(256) void k5b(const float* __restrict__ HT,
                                           const float* __restrict__ bw1,
                                           const float* __restrict__ w2,
                                           const float* __restrict__ bw2,
                                           float* __restrict__ COEF,
                                           float* __restrict__ out) {
    int b = blockIdx.x * 256 + threadIdx.x;
    float z = bw2[0];
#pragma unroll
    for (int j = 0; j < HIDN; ++j) {
        float h = fmaxf(HT[(size_t)j * BN + b] + bw1[j], 0.f);
        z = fmaf(w2[j], h, z);
    }
    float cf = 1.f / (1.f + expf(-z));
    COEF[b] = cf;
    out[(size_t)BN * DD + b] = cf;
}

__device__ inline float dotu(const float4* ur, const float* t, float b) {
    float a = b;
#pragma unroll
    for (int rr = 0; rr < 4; ++rr) {
        a = fmaf(ur[rr].x, t[4 * rr + 0], a);
        a = fmaf(ur[rr].y, t[4 * rr + 1], a);
        a = fmaf(ur[rr].z, t[4 * rr + 2], a);
        a = fmaf(ur[rr].w, t[4 * rr + 3], a);
    }
    return a;
}

// ---------------- K6f: fused row norms + blend + store ----------------------
// 1024-thread block spans a full 16x4096 row tile; computes XN2/X0N2 in-block
// (replaces k4 and k2m's X0N2 path).
__global__ __launch_bounds__(1024) void k6f(const float* __restrict__ grad,
                                            const float* __restrict__ meanw,
                                            const float* __restrict__ invw,
                                            const float* __restrict__ T1T,
                                            const float* __restrict__ u1,
                                            const float* __restrict__ b1,
                                            const float* __restrict__ COEF,
                                            float* __restrict__ out) {
    __shared__ float redn[2][16];
    __shared__ float bc[2];
    int tid = threadIdx.x;
    int wv = tid >> 6, l = tid & 63;
    int row0 = blockIdx.x * 16;
    int c = tid * 4;
    float4 u[4][4];
#pragma unroll
    for (int cc = 0; cc < 4; ++cc)
#pragma unroll
        for (int rr = 0; rr < 4; ++rr)
            u[cc][rr] = *(const float4*)(u1 + (size_t)(c + cc) * RK + rr * 4);
    float4 bv = *(const float4*)(b1 + c);
    float4 mv = *(const float4*)(meanw + c);
    float4 iv = *(const float4*)(invw + c);

    for (int row = 0; row < 16; ++row) {
        int b = row0 + row;
        float t[16];
#pragma unroll
        for (int r = 0; r < 16; ++r) t[r] = T1T[(size_t)r * BN + b];  // uniform
        float4 g = *(const float4*)(grad + (size_t)b * DD + c);
        float4 x0;
        x0.x = (g.x - mv.x) * iv.x;
        x0.y = (g.y - mv.y) * iv.y;
        x0.z = (g.z - mv.z) * iv.z;
        x0.w = (g.w - mv.w) * iv.w;
        float4 x2;
        x2.x = fmaxf(dotu(u[0], t, bv.x), 0.f);
        x2.y = fmaxf(dotu(u[1], t, bv.y), 0.f);
        x2.z = fmaxf(dotu(u[2], t, bv.z), 0.f);
        x2.w = fmaxf(dotu(u[3], t, bv.w), 0.f);
        float s0 = x0.x * x0.x + x0.y * x0.y + x0.z * x0.z + x0.w * x0.w;
        float s2 = x2.x * x2.x + x2.y * x2.y + x2.z * x2.z + x2.w * x2.w;
#pragma unroll
        for (int off = 1; off < 64; off <<= 1) {
            s0 += __shfl_xor(s0, off);
            s2 += __shfl_xor(s2, off);
        }
        if (l == 0) {
            redn[0][wv] = s2;
            redn[1][wv] = s0;
        }
        __syncthreads();
        if (tid < 16) {
            float a2 = redn[0][tid], a0 = redn[1][tid];
#pragma unroll
            for (int off = 1; off < 16; off <<= 1) {
                a2 += __shfl_xor(a2, off);
                a0 += __shfl_xor(a0, off);
            }
            if (tid == 0) {
                float xn = sqrtf(a2) + 1e-8f;
                float x0n = sqrtf(a0) + 1e-8f;
                float cf = COEF[b];
                bc[0] = (1.f - cf) * x0n / xn;
                bc[1] = cf;
            }
        }
        __syncthreads();
        float s1 = bc[0], cf = bc[1];
        float4 o;
        o.x = fmaf(s1, x2.x, cf * x0.x);
        o.y = fmaf(s1, x2.y, cf * x0.y);
        o.z = fmaf(s1, x2.z, cf * x0.z);
        o.w = fmaf(s1, x2.w, cf * x0.w);
        *(float4*)(out + (size_t)b * DD + c) = o;
    }
}

extern "C" void kernel_launch(void* const* d_in, const int* in_sizes, int n_in,
                              void* d_out, int out_size, void* d_ws, size_t ws_size,
                              hipStream_t stream) {
    const float* grad = (const float*)d_in[0];
    const float* embed = (const float*)d_in[1];
    const float* u0 = (const float*)d_in[2];
    const float* v0 = (const float*)d_in[3];
    const float* b0 = (const float*)d_in[4];
    const float* u1 = (const float*)d_in[5];
    const float* v1 = (const float*)d_in[6];
    const float* b1 = (const float*)d_in[7];
    const float* w1 = (const float*)d_in[8];
    const float* bw1 = (const float*)d_in[9];
    const float* w2 = (const float*)d_in[10];
    const float* bw2 = (const float*)d_in[11];
    float* out = (float*)d_out;
    float* ws = (float*)d_ws;

    hipMemsetAsync(ws, 0, (size_t)ZCOUNT * sizeof(float), stream);

    kT<<<16, 256, 0, stream>>>(v1, ws + OFF_V1T);
    // embed pass first so grad (read by k1a just before k2m) stays L3-resident
    k5m<<<2048, 256, 0, stream>>>(embed, w1, ws + OFF_HT);
    k1a<<<512, 256, 0, stream>>>(grad, ws + OFF_PS, ws + OFF_PQ);
    k1b<<<16, 256, 0, stream>>>(ws + OFF_PS, ws + OFF_PQ, ws + OFF_MEAN, ws + OFF_INV);
    k2m<<<2048, 256, 0, stream>>>(grad, ws + OFF_MEAN, ws + OFF_INV, v0, ws + OFF_T0T);
    k3<<<1024, 256, 0, stream>>>(ws + OFF_T0T, u0, b0, ws + OFF_V1T, ws + OFF_T1T);
    k5b<<<32, 256, 0, stream>>>(ws + OFF_HT, bw1, w2, bw2, ws + OFF_COEF, out);
    k6f<<<512, 1024, 0, stream>>>(grad, ws + OFF_MEAN, ws + OFF_INV, ws + OFF_T1T,
                                  u1, b1, ws + OFF_COEF, out);
}

// Round 5
// 491.641 us; speedup vs baseline: 1.4005x; 1.0059x over previous
//
#include <hip/hip_runtime.h>
#include <math.h>

#define BN 8192
#define DD 4096
#define RK 16
#define HIDN 24
#define NCHUNK 128

// ws layout (float offsets). ps/pq have their own region (no aliasing).
#define OFF_T0T  0                           // 16*BN = 131072
#define OFF_T1T  (OFF_T0T + RK*BN)           // 131072
#define OFF_HT   (OFF_T1T + RK*BN)           // 262144 (32*BN, j-major)
#define ZCOUNT   (OFF_HT + 32*BN)            // 524288 zeroed (atomic targets)
#define OFF_PS   (ZCOUNT)                    // 128*DD = 524288
#define OFF_PQ   (OFF_PS + NCHUNK*DD)        // 524288
#define OFF_V1T  (OFF_PQ + NCHUNK*DD)        // 65536
#define OFF_MEAN (OFF_V1T + DD*RK)
#define OFF_INV  (OFF_MEAN + DD)

typedef __attribute__((ext_vector_type(8))) __bf16 bf16x8;
typedef __attribute__((ext_vector_type(4))) float f32x4;

// f32x8 -> bf16 hi + residual-lo frags (RNE via compiler casts)
__device__ inline void split8(const float* p, bf16x8& hi, bf16x8& lo) {
    float4 a = *(const float4*)p;
    float4 b = *(const float4*)(p + 4);
    float v[8] = {a.x, a.y, a.z, a.w, b.x, b.y, b.z, b.w};
#pragma unroll
    for (int j = 0; j < 8; ++j) {
        __bf16 h = (__bf16)v[j];
        hi[j] = h;
        lo[j] = (__bf16)(v[j] - (float)h);
    }
}

// ---------------- K1a: per-column partial sums, float4, 64-row chunks -------
__global__ __launch_bounds__(256) void k1a(const float* __restrict__ g,
                                           float* __restrict__ ps,
                                           float* __restrict__ pq) {
    int ct = blockIdx.x & 3, rc = blockIdx.x >> 2;   // 4 col-tiles x 128 chunks
    int col = ct * 1024 + threadIdx.x * 4;
    size_t base = (size_t)rc * 64 * DD + col;
    float4 s1 = make_float4(0.f, 0.f, 0.f, 0.f);
    float4 s2 = make_float4(0.f, 0.f, 0.f, 0.f);
#pragma unroll 8
    for (int i = 0; i < 64; ++i) {
        float4 v = *(const float4*)(g + base + (size_t)i * DD);
        s1.x += v.x; s1.y += v.y; s1.z += v.z; s1.w += v.w;
        s2.x = fmaf(v.x, v.x, s2.x);
        s2.y = fmaf(v.y, v.y, s2.y);
        s2.z = fmaf(v.z, v.z, s2.z);
        s2.w = fmaf(v.w, v.w, s2.w);
    }
    *(float4*)(ps + (size_t)rc * DD + col) = s1;
    *(float4*)(pq + (size_t)rc * DD + col) = s2;
}

// ---------------- K1bT: finalize mean / inv-std + v1 transpose --------------
// Same grid/mapping as old kT (one thread per d) -> fold the transpose in.
__global__ __launch_bounds__(256) void k1bT(const float* __restrict__ ps,
                                            const float* __restrict__ pq,
                                            const float* __restrict__ v1,
                                            float* __restrict__ meanw,
                                            float* __restrict__ invw,
                                            float* __restrict__ v1T) {
    int d = blockIdx.x * 256 + threadIdx.x;
    float s1 = 0.f, s2 = 0.f;
#pragma unroll 8
    for (int i = 0; i < NCHUNK; ++i) {
        s1 += ps[i * DD + d];
        s2 += pq[i * DD + d];
    }
    float mean = s1 / (float)BN;
    float var = (s2 - s1 * s1 / (float)BN) / (float)(BN - 1);
    var = fmaxf(var, 0.f);
    meanw[d] = mean;
    invw[d] = 1.f / (sqrtf(var) + 1e-7f);
    float v[16];
#pragma unroll
    for (int s = 0; s < 16; ++s) v[s] = v1[(size_t)s * DD + d];
#pragma unroll
    for (int s = 0; s < 4; ++s)
        *(float4*)(v1T + (size_t)d * 16 + s * 4) =
            make_float4(v[4 * s], v[4 * s + 1], v[4 * s + 2], v[4 * s + 3]);
}

// ---------------- K2m: MFMA  T0T[r][b] += v0 · x0 ---------------------------
// 16-row m-groups (grid 2048 = 512 m x 4 K-quarters) for 8 blocks/CU.
__global__ __launch_bounds__(256) void k2m(const float* __restrict__ grad,
                                           const float* __restrict__ meanw,
                                           const float* __restrict__ invw,
                                           const float* __restrict__ v0,
                                           float* __restrict__ T0T) {
    __shared__ float red[4][256];
    int tid = threadIdx.x;
    int wv = tid >> 6, l = tid & 63;
    int lr = l & 15, lk = l >> 4;
    int m0 = (blockIdx.x >> 2) * 16;
    int kbase = (blockIdx.x & 3) * 1024 + wv * 256;
    const float* g0 = grad + (size_t)(m0 + lr) * DD + kbase + lk * 8;
    const float* vp = v0 + (size_t)lr * DD + kbase + lk * 8;
    const float* mp = meanw + kbase + lk * 8;
    const float* ip = invw + kbase + lk * 8;
    f32x4 acc = {0.f, 0.f, 0.f, 0.f};
#pragma unroll 2
    for (int ks = 0; ks < 8; ++ks) {
        int k0 = ks * 32;
        bf16x8 vhi, vlo;
        split8(vp + k0, vhi, vlo);
        float4 ma = *(const float4*)(mp + k0);
        float4 mb = *(const float4*)(mp + k0 + 4);
        float4 ia = *(const float4*)(ip + k0);
        float4 ib = *(const float4*)(ip + k0 + 4);
        float mv[8] = {ma.x, ma.y, ma.z, ma.w, mb.x, mb.y, mb.z, mb.w};
        float iv[8] = {ia.x, ia.y, ia.z, ia.w, ib.x, ib.y, ib.z, ib.w};
        float4 ga = *(const float4*)(g0 + k0);
        float4 gb = *(const float4*)(g0 + k0 + 4);
        float gv[8] = {ga.x, ga.y, ga.z, ga.w, gb.x, gb.y, gb.z, gb.w};
        bf16x8 xhi, xlo;
#pragma unroll
        for (int j = 0; j < 8; ++j) {
            float x = (gv[j] - mv[j]) * iv[j];
            __bf16 h = (__bf16)x;
            xhi[j] = h;
            xlo[j] = (__bf16)(x - (float)h);
        }
        acc = __builtin_amdgcn_mfma_f32_16x16x32_bf16(vhi, xhi, acc, 0, 0, 0);
        acc = __builtin_amdgcn_mfma_f32_16x16x32_bf16(vhi, xlo, acc, 0, 0, 0);
        acc = __builtin_amdgcn_mfma_f32_16x16x32_bf16(vlo, xhi, acc, 0, 0, 0);
    }
#pragma unroll
    for (int r = 0; r < 4; ++r)
        red[wv][(lk * 4 + r) * 16 + lr] = acc[r];
    __syncthreads();
    float s = red[0][tid] + red[1][tid] + red[2][tid] + red[3][tid];
    atomicAdd(&T0T[(size_t)(tid >> 4) * BN + m0 + (tid & 15)], s);
}

// ---------------- K3: T1T[s][b] += v1T·relu(b0+u0·t0)  (no LDS) -------------
__global__ __launch_bounds__(256) void k3(const float* __restrict__ T0T,
                                          const float* __restrict__ u0,
                                          const float* __restrict__ b0,
                                          const float* __restrict__ v1T,
                                          float* __restrict__ T1T) {
    int b = (blockIdx.x >> 5) * 256 + threadIdx.x;
    int d0 = (blockIdx.x & 31) * 128;
    float t0[16];
#pragma unroll
    for (int r = 0; r < 16; ++r) t0[r] = T0T[(size_t)r * BN + b];
    float acc[16];
#pragma unroll
    for (int s = 0; s < 16; ++s) acc[s] = 0.f;
#pragma unroll 2
    for (int d = d0; d < d0 + 128; ++d) {
        const float* ur = u0 + (size_t)d * RK;       // uniform
        float x1 = b0[d];
#pragma unroll
        for (int r = 0; r < 16; ++r) x1 = fmaf(ur[r], t0[r], x1);
        x1 = fmaxf(x1, 0.f);
        const float* vr = v1T + (size_t)d * RK;      // uniform
#pragma unroll
        for (int s = 0; s < 16; ++s) acc[s] = fmaf(vr[s], x1, acc[s]);
    }
#pragma unroll
    for (int s = 0; s < 16; ++s)
        atomicAdd(&T1T[(size_t)s * BN + b], acc[s]);
}

// ---------------- K5m: MFMA  HT[j][b] += w1 · embed^T -----------------------
// 16-row m-groups (grid 2048) for 8 blocks/CU. N=24 padded to 32 (clamped).
__global__ __launch_bounds__(256) void k5m(const float* __restrict__ embed,
                                           const float* __restrict__ w1,
                                           float* __restrict__ HT) {
    __shared__ float red[4][512];
    int tid = threadIdx.x;
    int wv = tid >> 6, l = tid & 63;
    int lr = l & 15, lk = l >> 4;
    int m0 = (blockIdx.x >> 2) * 16;
    int kbase = (blockIdx.x & 3) * 1024 + wv * 256;
    int wr1 = (lr + 16 > 23) ? 23 : lr + 16;         // clamp pad rows
    const float* e0 = embed + (size_t)(m0 + lr) * DD + kbase + lk * 8;
    const float* w0a = w1 + (size_t)lr * DD + kbase + lk * 8;
    const float* w0b = w1 + (size_t)wr1 * DD + kbase + lk * 8;
    f32x4 acc0 = {0.f, 0.f, 0.f, 0.f};
    f32x4 acc1 = {0.f, 0.f, 0.f, 0.f};
#pragma unroll 2
    for (int ks = 0; ks < 8; ++ks) {
        int k0 = ks * 32;
        bf16x8 whi0, wlo0, whi1, wlo1, ehi, elo;
        split8(w0a + k0, whi0, wlo0);
        split8(w0b + k0, whi1, wlo1);
        split8(e0 + k0, ehi, elo);
        acc0 = __builtin_amdgcn_mfma_f32_16x16x32_bf16(whi0, ehi, acc0, 0, 0, 0);
        acc1 = __builtin_amdgcn_mfma_f32_16x16x32_bf16(whi1, ehi, acc1, 0, 0, 0);
        acc0 = __builtin_amdgcn_mfma_f32_16x16x32_bf16(whi0, elo, acc0, 0, 0, 0);
        acc1 = __builtin_amdgcn_mfma_f32_16x16x32_bf16(whi1, elo, acc1, 0, 0, 0);
        acc0 = __builtin_amdgcn_mfma_f32_16x16x32_bf16(wlo0, ehi, acc0, 0, 0, 0);
        acc1 = __builtin_amdgcn_mfma_f32_16x16x32_bf16(wlo1, ehi, acc1, 0, 0, 0);
    }
#pragma unroll
    for (int r = 0; r < 4; ++r) {
        red[wv][(lk * 4 + r) * 16 + lr] = acc0[r];
        red[wv][256 + (lk * 4 + r) * 16 + lr] = acc1[r];
    }
    __syncthreads();
#pragma unroll
    for (int j = 0; j < 2; ++j) {
        int idx = tid + j * 256;
        float s = red[0][idx] + red[1][idx] + red[2][idx] + red[3][idx];
        int nt = idx >> 8, nr = (idx >> 4) & 15, cc = idx & 15;
        atomicAdd(&HT[(size_t)(nt * 16 + nr) * BN + m0 + cc], s);
    }
}

__device__ inline float dotu(const float4* ur, const float* t, float b) {
    float a = b;
#pragma unroll
    for (int rr = 0; rr < 4; ++rr) {
        a = fmaf(ur[rr].x, t[4 * rr + 0], a);
        a = fmaf(ur[rr].y, t[4 * rr + 1], a);
        a = fmaf(ur[rr].z, t[4 * rr + 2], a);
        a = fmaf(ur[rr].w, t[4 * rr + 3], a);
    }
    return a;
}

// ---------------- K6fc: coeff head + fused row norms + blend + store --------
// Threads 0-15 compute coeff (old k5b body) for the block's 16 rows into cfs;
// row loop then proceeds as the proven k6f with cf = cfs[row].
__global__ __launch_bounds__(1024) void k6fc(const float* __restrict__ grad,
                                             const float* __restrict__ meanw,
                                             const float* __restrict__ invw,
                                             const float* __restrict__ T1T,
                                             const float* __restrict__ u1,
                                             const float* __restrict__ b1,
                                             const float* __restrict__ HT,
                                             const float* __restrict__ bw1,
                                             const float* __restrict__ w2,
                                             const float* __restrict__ bw2,
                                             float* __restrict__ out) {
    __shared__ float redn[2][16];
    __shared__ float bc[2];
    __shared__ float cfs[16];
    int tid = threadIdx.x;
    int wv = tid >> 6, l = tid & 63;
    int row0 = blockIdx.x * 16;
    int c = tid * 4;

    if (tid < 16) {                                   // coeff head (old k5b)
        int b = row0 + tid;
        float z = bw2[0];
#pragma unroll
        for (int j = 0; j < HIDN; ++j) {
            float h = fmaxf(HT[(size_t)j * BN + b] + bw1[j], 0.f);
            z = fmaf(w2[j], h, z);
        }
        float cf = 1.f / (1.f + expf(-z));
        cfs[tid] = cf;
        out[(size_t)BN * DD + b] = cf;
    }

    float4 u[4][4];
#pragma unroll
    for (int cc = 0; cc < 4; ++cc)
#pragma unroll
        for (int rr = 0; rr < 4; ++rr)
            u[cc][rr] = *(const float4*)(u1 + (size_t)(c + cc) * RK + rr * 4);
    float4 bv = *(const float4*)(b1 + c);
    float4 mv = *(const float4*)(meanw + c);
    float4 iv = *(const float4*)(invw + c);
    __syncthreads();

    for (int row = 0; row < 16; ++row) {
        int b = row0 + row;
        float t[16];
#pragma unroll
        for (int r = 0; r < 16; ++r) t[r] = T1T[(size_t)r * BN + b];  // uniform
        float4 g = *(const float4*)(grad + (size_t)b * DD + c);
        float4 x0;
        x0.x = (g.x - mv.x) * iv.x;
        x0.y = (g.y - mv.y) * iv.y;
        x0.z = (g.z - mv.z) * iv.z;
        x0.w = (g.w - mv.w) * iv.w;
        float4 x2;
        x2.x = fmaxf(dotu(u[0], t, bv.x), 0.f);
        x2.y = fmaxf(dotu(u[1], t, bv.y), 0.f);
        x2.z = fmaxf(dotu(u[2], t, bv.z), 0.f);
        x2.w = fmaxf(dotu(u[3], t, bv.w), 0.f);
        float s0 = x0.x * x0.x + x0.y * x0.y + x0.z * x0.z + x0.w * x0.w;
        float s2 = x2.x * x2.x + x2.y * x2.y + x2.z * x2.z + x2.w * x2.w;
#pragma unroll
        for (int off = 1; off < 64; off <<= 1) {
            s0 += __shfl_xor(s0, off);
            s2 += __shfl_xor(s2, off);
        }
        if (l == 0) {
            redn[0][wv] = s2;
            redn[1][wv] = s0;
        }
        __syncthreads();
        if (tid < 16) {
            float a2 = redn[0][tid], a0 = redn[1][tid];
#pragma unroll
            for (int off = 1; off < 16; off <<= 1) {
                a2 += __shfl_xor(a2, off);
                a0 += __shfl_xor(a0, off);
            }
            if (tid == 0) {
                float xn = sqrtf(a2) + 1e-8f;
                float x0n = sqrtf(a0) + 1e-8f;
                float cf = cfs[row];
                bc[0] = (1.f - cf) * x0n / xn;
                bc[1] = cf;
            }
        }
        __syncthreads();
        float s1 = bc[0], cf = bc[1];
        float4 o;
        o.x = fmaf(s1, x2.x, cf * x0.x);
        o.y = fmaf(s1, x2.y, cf * x0.y);
        o.z = fmaf(s1, x2.z, cf * x0.z);
        o.w = fmaf(s1, x2.w, cf * x0.w);
        *(float4*)(out + (size_t)b * DD + c) = o;
    }
}

extern "C" void kernel_launch(void* const* d_in, const int* in_sizes, int n_in,
                              void* d_out, int out_size, void* d_ws, size_t ws_size,
                              hipStream_t stream) {
    const float* grad = (const float*)d_in[0];
    const float* embed = (const float*)d_in[1];
    const float* u0 = (const float*)d_in[2];
    const float* v0 = (const float*)d_in[3];
    const float* b0 = (const float*)d_in[4];
    const float* u1 = (const float*)d_in[5];
    const float* v1 = (const float*)d_in[6];
    const float* b1 = (const float*)d_in[7];
    const float* w1 = (const float*)d_in[8];
    const float* bw1 = (const float*)d_in[9];
    const float* w2 = (const float*)d_in[10];
    const float* bw2 = (const float*)d_in[11];
    float* out = (float*)d_out;
    float* ws = (float*)d_ws;

    hipMemsetAsync(ws, 0, (size_t)ZCOUNT * sizeof(float), stream);

    // embed pass first so grad (read by k1a, then k2m) stays L3-resident
    k5m<<<2048, 256, 0, stream>>>(embed, w1, ws + OFF_HT);
    k1a<<<512, 256, 0, stream>>>(grad, ws + OFF_PS, ws + OFF_PQ);
    k1bT<<<16, 256, 0, stream>>>(ws + OFF_PS, ws + OFF_PQ, v1,
                                 ws + OFF_MEAN, ws + OFF_INV, ws + OFF_V1T);
    k2m<<<2048, 256, 0, stream>>>(grad, ws + OFF_MEAN, ws + OFF_INV, v0, ws + OFF_T0T);
    k3<<<1024, 256, 0, stream>>>(ws + OFF_T0T, u0, b0, ws + OFF_V1T, ws + OFF_T1T);
    k6fc<<<512, 1024, 0, stream>>>(grad, ws + OFF_MEAN, ws + OFF_INV, ws + OFF_T1T,
                                   u1, b1, ws + OFF_HT, bw1, w2, bw2, out);
}